// Round 1
// baseline (2153.131 us; speedup 1.0000x reference)
//
#include <hip/hip_runtime.h>
#include <math.h>

typedef float v2f __attribute__((ext_vector_type(2)));
typedef float v4f __attribute__((ext_vector_type(4)));

#define C_DIM 256
#define K_DIM 8192
#define HW    1024      // 32*32
#define N_OUT 8388608   // 32*256*32*32

// ---------------------------------------------------------------------------
// Kernel 1: e_norm[k] = sum_c embed[c][k]^2   (coalesced across k per c)
// ---------------------------------------------------------------------------
__global__ void enorm_kernel(const float* __restrict__ embed,
                             float* __restrict__ e_norm) {
    int k = blockIdx.x * 256 + threadIdx.x;
    float s = 0.f;
    #pragma unroll 8
    for (int c = 0; c < C_DIM; ++c) {
        float v = embed[c * K_DIM + k];
        s = __builtin_fmaf(v, v, s);
    }
    e_norm[k] = s;
}

// ---------------------------------------------------------------------------
// Stage one E chunk (64 c x 128 k floats = 32KB) via global_load_lds width=16.
// LDS float offset = tid*4 + l*1024  -> linear in tid: wave-uniform base + lane*16B. OK.
// ---------------------------------------------------------------------------
__device__ __forceinline__ void stage_chunk(const float* __restrict__ embed,
                                            float* dst, int k0, int c0, int tid) {
    const float* src = embed + (c0 + (tid >> 5)) * K_DIM + k0 + ((tid & 31) << 2);
    #pragma unroll
    for (int l = 0; l < 8; ++l) {
        __builtin_amdgcn_global_load_lds(
            (const __attribute__((address_space(1))) void*)(src + l * 8 * K_DIM),
            (__attribute__((address_space(3))) void*)(dst + ((tid >> 6) << 8) + (l << 10)),
            16, 0, 0);
    }
}

// ---------------------------------------------------------------------------
// Main kernel: 512 blocks x 256 threads. Block = (b, t0): 64 rows (t = t0..t0+63,
// t = h*32 + w), full scan over 8192 codes in 128-col tiles, C chunked by 64.
// Thread tile: 4 rows x 8 cols (cols cg*4..+3 and 64+cg*4..+3).
// ---------------------------------------------------------------------------
__launch_bounds__(256, 1)
__global__ void vq_kernel(const float* __restrict__ x,
                          const float* __restrict__ embed,
                          const float* __restrict__ e_norm,
                          float* __restrict__ out,
                          float* __restrict__ ids_out) {
    __shared__ float A[C_DIM * 64];     // [c][r], stride 64 floats -> bank = r%32
    __shared__ float E[2][64 * 128];    // [cc][j], double-buffered
    __shared__ float z2s[64];
    __shared__ int   ids_lds[64];

    const int tid  = threadIdx.x;
    const int blk  = blockIdx.x;
    const int b    = blk >> 4;
    const int t0   = (blk & 15) << 6;

    const int t_off = tid & 63;
    const int w4    = tid >> 6;       // 0..3
    const int rg    = tid >> 4;       // 0..15 : rows rg*4 .. rg*4+3
    const int cg    = tid & 15;       // 0..15 : cols cg*4 and 64+cg*4

    // async prologue stage of chunk (k0=0, c0=0) into E[0]
    stage_chunk(embed, &E[0][0], 0, 0, tid);

    // stage A[c][r] from x[b, c, h, w] with t = h*32+w  (coalesced: addr = c*1024 + t)
    {
        const float* xb = x + b * (C_DIM * HW) + t0;
        #pragma unroll 4
        for (int c = w4; c < C_DIM; c += 4)
            A[(c << 6) + t_off] = xb[c * HW + t_off];
    }
    asm volatile("s_waitcnt vmcnt(0)" ::: "memory");
    __syncthreads();

    // z2 per row (mimics jnp.sum(flatten*flatten, axis=1))
    if (tid < 64) {
        float s = 0.f;
        #pragma unroll 8
        for (int c = 0; c < C_DIM; ++c) {
            float v = A[(c << 6) + tid];
            s = __builtin_fmaf(v, v, s);
        }
        z2s[tid] = s;
    }
    __syncthreads();

    float z2r[4];
    #pragma unroll
    for (int r = 0; r < 4; ++r) z2r[r] = z2s[(rg << 2) + r];

    float minv[4] = { INFINITY, INFINITY, INFINITY, INFINITY };
    int   mini[4] = { 0, 0, 0, 0 };

    int buf = 0;
    for (int k0 = 0; k0 < K_DIM; k0 += 128) {
        v2f acc[4][4];
        #pragma unroll
        for (int r = 0; r < 4; ++r)
            #pragma unroll
            for (int p = 0; p < 4; ++p) acc[r][p] = (v2f){0.f, 0.f};

        #pragma unroll
        for (int ch = 0; ch < 4; ++ch) {
            // issue next chunk's async stage into the other buffer
            int nch = ch + 1, nk0 = k0;
            if (nch == 4) { nch = 0; nk0 += 128; }
            if (nk0 < K_DIM) stage_chunk(embed, &E[buf ^ 1][0], nk0, nch << 6, tid);

            const float* Ap = &A[((ch << 6) << 6) + (rg << 2)];
            const float* Ep = &E[buf][cg << 2];
            #pragma unroll 4
            for (int cc = 0; cc < 64; ++cc) {
                v4f a4 = *(const v4f*)Ap;
                v4f eA = *(const v4f*)Ep;
                v4f eB = *(const v4f*)(Ep + 64);
                Ap += 64; Ep += 128;
                #pragma unroll
                for (int r = 0; r < 4; ++r) {
                    v2f ar = { a4[r], a4[r] };
                    acc[r][0] = __builtin_elementwise_fma(ar, (v2f){eA[0], eA[1]}, acc[r][0]);
                    acc[r][1] = __builtin_elementwise_fma(ar, (v2f){eA[2], eA[3]}, acc[r][1]);
                    acc[r][2] = __builtin_elementwise_fma(ar, (v2f){eB[0], eB[1]}, acc[r][2]);
                    acc[r][3] = __builtin_elementwise_fma(ar, (v2f){eB[2], eB[3]}, acc[r][3]);
                }
            }
            asm volatile("s_waitcnt vmcnt(0)" ::: "memory");
            __syncthreads();
            buf ^= 1;
        }

        // dist = (e2 + z2) - 2*dot, ascending column order, strict '<' keeps first idx
        #pragma unroll
        for (int p = 0; p < 4; ++p) {
            const int jb = k0 + ((p >> 1) << 6) + (cg << 2) + ((p & 1) << 1);
            const float e2a = e_norm[jb];
            const float e2b = e_norm[jb + 1];
            #pragma unroll
            for (int r = 0; r < 4; ++r) {
                float d0 = __fadd_rn(__fadd_rn(e2a, z2r[r]), -__fmul_rn(2.0f, acc[r][p][0]));
                float d1 = __fadd_rn(__fadd_rn(e2b, z2r[r]), -__fmul_rn(2.0f, acc[r][p][1]));
                if (d0 < minv[r]) { minv[r] = d0; mini[r] = jb; }
                if (d1 < minv[r]) { minv[r] = d1; mini[r] = jb + 1; }
            }
        }
    }

    // cross-thread argmin reduce over the 16 col-groups (lane bits 0..3)
    #pragma unroll
    for (int r = 0; r < 4; ++r) {
        float m = minv[r]; int mi = mini[r];
        #pragma unroll
        for (int d = 1; d < 16; d <<= 1) {
            float om = __shfl_xor(m, d, 64);
            int   oi = __shfl_xor(mi, d, 64);
            if (om < m || (om == m && oi < mi)) { m = om; mi = oi; }
        }
        if (cg == 0) ids_lds[(rg << 2) + r] = mi;
    }
    __syncthreads();

    // ids output: ids_flat[n] = id(n), n = b*1024 + (t&31)*32 + (t>>5)
    if (tid < 64) {
        int t = t0 + tid;
        int n = (b << 10) + ((t & 31) << 5) + (t >> 5);
        ids_out[n] = (float)ids_lds[tid];
    }

    // out[b, c, h, w] = embed[c, id]; writes coalesced over t, reads gather (L2/L3-hot)
    const int myid = ids_lds[t_off];
    const float* ecol = embed + myid;
    float* ob = out + b * (C_DIM * HW) + t0 + t_off;
    #pragma unroll 4
    for (int c = w4; c < C_DIM; c += 4)
        ob[c * HW] = ecol[c * K_DIM];
}

extern "C" void kernel_launch(void* const* d_in, const int* in_sizes, int n_in,
                              void* d_out, int out_size, void* d_ws, size_t ws_size,
                              hipStream_t stream) {
    const float* x     = (const float*)d_in[0];
    const float* embed = (const float*)d_in[1];
    float* out   = (float*)d_out;
    float* ids   = out + N_OUT;
    float* enorm = (float*)d_ws;

    enorm_kernel<<<K_DIM / 256, 256, 0, stream>>>(embed, enorm);
    vq_kernel<<<512, 256, 0, stream>>>(x, embed, enorm, out, ids);
}

// Round 3
// 1181.120 us; speedup vs baseline: 1.8230x; 1.8230x over previous
//
#include <hip/hip_runtime.h>
#include <math.h>

typedef float f32x4 __attribute__((ext_vector_type(4)));
typedef __attribute__((ext_vector_type(8))) short short8;

#define C_DIM   256
#define K_DIM   8192
#define HW      1024
#define N_ROWS  32768
#define N_OUT   8388608
#define TAU     0.05f

// ---------------- bf16 split helpers (RN-even) ----------------
__device__ __forceinline__ unsigned short f2bf(float v) {
    union { float f; unsigned u; } a; a.f = v;
    unsigned r = a.u + 0x7fffu + ((a.u >> 16) & 1u);
    return (unsigned short)(r >> 16);
}
__device__ __forceinline__ float bf2f(unsigned short b) {
    union { float f; unsigned u; } a; a.u = ((unsigned)b) << 16; return a.f;
}

// Fragment-packed buffers (ushort units):
//   buf[tile][ck 0..15][frag 0..7][lane 0..63][elem 0..7]
//   ck stride 4096, frag stride 512, lane stride 8; tile stride 65536 (128 rows/cols).
// hi parts at ck 0..7, lo parts at ck 8..15; ck covers 32 channels (lane>>4)*8+e.
// mfma_f32_16x16x32_bf16 A/B: lane l -> row/col = l&15, k = (l>>4)*8+e.

__global__ void enorm_kernel(const float* __restrict__ embed, float* __restrict__ e_norm) {
    int k = blockIdx.x * 256 + threadIdx.x;
    float s = 0.f;
    #pragma unroll 8
    for (int c = 0; c < C_DIM; ++c) { float v = embed[c * K_DIM + k]; s = __builtin_fmaf(v, v, s); }
    e_norm[k] = s;
}

__global__ void z2_kernel(const float* __restrict__ x, float* __restrict__ z2) {
    int r = blockIdx.x * 256 + threadIdx.x;
    int b = r >> 10, t = r & 1023;
    const float* xb = x + b * (C_DIM * HW) + t;
    float s = 0.f;
    #pragma unroll 8
    for (int c = 0; c < C_DIM; ++c) { float v = xb[c << 10]; s = __builtin_fmaf(v, v, s); }
    z2[r] = s;
}

__global__ void prepA_kernel(const float* __restrict__ x, unsigned short* __restrict__ abuf) {
    int blk = blockIdx.x;           // 2048 = mt(256) x ckh(8)
    int mt = blk >> 3, ckh = blk & 7;
    #pragma unroll
    for (int u = 0; u < 2; ++u) {
        int unit = threadIdx.x + u * 256;   // frag(8) x lane(64)
        int f = unit >> 6, l = unit & 63;
        int row = (mt << 7) + (f << 4) + (l & 15);
        int b = row >> 10, t = row & 1023;
        int cb = (ckh << 5) + ((l >> 4) << 3);
        const float* xp = x + (((b << 8) + cb) << 10) + t;
        short8 hi, lo;
        #pragma unroll
        for (int j = 0; j < 8; ++j) {
            float v = xp[j << 10];
            unsigned short h = f2bf(v);
            hi[j] = (short)h;
            lo[j] = (short)f2bf(v - bf2f(h));
        }
        unsigned long base = ((unsigned long)mt * 16u + ckh) * 4096u + (unsigned)f * 512u + (unsigned)l * 8u;
        *(short8*)(abuf + base)              = hi;
        *(short8*)(abuf + base + 8u * 4096u) = lo;
    }
}

__global__ void prepE_kernel(const float* __restrict__ embed, unsigned short* __restrict__ ebuf) {
    int blk = blockIdx.x;           // 512 = nt(64) x ckh(8)
    int nt = blk >> 3, ckh = blk & 7;
    #pragma unroll
    for (int u = 0; u < 2; ++u) {
        int unit = threadIdx.x + u * 256;
        int f = unit >> 6, l = unit & 63;
        int col = (nt << 7) + (f << 4) + (l & 15);
        int cb = (ckh << 5) + ((l >> 4) << 3);
        const float* ep = embed + cb * K_DIM + col;
        short8 hi, lo;
        #pragma unroll
        for (int j = 0; j < 8; ++j) {
            float v = ep[j * K_DIM];
            unsigned short h = f2bf(v);
            hi[j] = (short)h;
            lo[j] = (short)f2bf(v - bf2f(h));
        }
        unsigned long base = ((unsigned long)nt * 16u + ckh) * 4096u + (unsigned)f * 512u + (unsigned)l * 8u;
        *(short8*)(ebuf + base)              = hi;
        *(short8*)(ebuf + base + 8u * 4096u) = lo;
    }
}

#define GLDS(S, D) __builtin_amdgcn_global_load_lds(                              \
        (const __attribute__((address_space(1))) void*)(S),                       \
        (__attribute__((address_space(3))) void*)(D), 16, 0, 0)

// stage 4 chunks {A_hi[kk], A_lo[kk], E_hi[kk], E_lo[kk]} (32KB) into dst
__device__ __forceinline__ void stage4(const unsigned short* __restrict__ aBase,
                                       const unsigned short* __restrict__ eTile,
                                       int kk, unsigned short* dst, int tid) {
    const int o = tid * 8;                                  // 16B per thread
    const unsigned short* sA0 = aBase + kk * 4096 + o;
    const unsigned short* sA1 = aBase + (8 + kk) * 4096 + o;
    const unsigned short* sE0 = eTile + kk * 4096 + o;
    const unsigned short* sE1 = eTile + (8 + kk) * 4096 + o;
    GLDS(sA0,        dst + o);
    GLDS(sA0 + 2048, dst + o + 2048);
    GLDS(sA1,        dst + 4096 + o);
    GLDS(sA1 + 2048, dst + 4096 + o + 2048);
    GLDS(sE0,        dst + 8192 + o);
    GLDS(sE0 + 2048, dst + 8192 + o + 2048);
    GLDS(sE1,        dst + 12288 + o);
    GLDS(sE1 + 2048, dst + 12288 + o + 2048);
}

// main: 128x128 tile bf16-split GEMM + fused exact per-wave top-2
// grid 512: mt = bid>>1 (128 rows), nh = bid&1 (4096 cols). 4 waves = 2m x 2n.
__launch_bounds__(256, 2)
__global__ void vq_main(const unsigned short* __restrict__ abuf,
                        const unsigned short* __restrict__ ebuf,
                        const float* __restrict__ e_norm,
                        const float* __restrict__ z2,
                        float4* __restrict__ res) {
    __shared__ unsigned short lbuf[2][16384];   // [Ahi|Alo|Ehi|Elo] x 4096 each
    __shared__ float e2s[4096];

    const int tid  = threadIdx.x;
    const int lane = tid & 63;
    const int wave = tid >> 6;
    const int wm   = wave >> 1, wn = wave & 1;
    const int mt   = blockIdx.x >> 1;
    const int nh   = blockIdx.x & 1;

    const unsigned short* aBase = abuf + (unsigned long)mt * 65536u;
    const unsigned short* eHalf = ebuf + (unsigned long)(nh * 32) * 65536u;

    stage4(aBase, eHalf, 0, lbuf[0], tid);      // prologue: ntl=0, kk=0

    #pragma unroll
    for (int i = 0; i < 16; ++i) e2s[tid + i * 256] = e_norm[nh * 4096 + tid + i * 256];

    const int rowbase = (mt << 7) + wm * 64 + ((lane >> 4) << 2);
    float z2r[16];
    #pragma unroll
    for (int mi = 0; mi < 4; ++mi)
        #pragma unroll
        for (int r = 0; r < 4; ++r) z2r[mi * 4 + r] = z2[rowbase + mi * 16 + r];

    float d1v[16], d2v[16]; int i1v[16], i2v[16];
    #pragma unroll
    for (int i = 0; i < 16; ++i) { d1v[i] = INFINITY; d2v[i] = INFINITY; i1v[i] = 0; i2v[i] = 0; }

    asm volatile("s_waitcnt vmcnt(0)" ::: "memory");   // drain prologue stage
    __syncthreads();

    int cur = 0;
    for (int ntl = 0; ntl < 32; ++ntl) {
        f32x4 acc[4][4];
        #pragma unroll
        for (int mi = 0; mi < 4; ++mi)
            #pragma unroll
            for (int ni = 0; ni < 4; ++ni) acc[mi][ni] = (f32x4){0.f, 0.f, 0.f, 0.f};

        for (int kk = 0; kk < 8; ++kk) {
            // prefetch next superphase into other buffer
            int nkk = kk + 1, nntl = ntl;
            if (nkk == 8) { nkk = 0; ++nntl; }
            if (nntl < 32)
                stage4(aBase, eHalf + (unsigned long)nntl * 65536u, nkk, lbuf[cur ^ 1], tid);

            const unsigned short* la = lbuf[cur];
            short8 ah[4], al[4], eh[4], el[4];
            #pragma unroll
            for (int mi = 0; mi < 4; ++mi) {
                ah[mi] = *(const short8*)(la +        (wm * 4 + mi) * 512 + lane * 8);
                al[mi] = *(const short8*)(la + 4096 + (wm * 4 + mi) * 512 + lane * 8);
            }
            #pragma unroll
            for (int ni = 0; ni < 4; ++ni) {
                eh[ni] = *(const short8*)(la + 8192  + (wn * 4 + ni) * 512 + lane * 8);
                el[ni] = *(const short8*)(la + 12288 + (wn * 4 + ni) * 512 + lane * 8);
            }
            #pragma unroll
            for (int mi = 0; mi < 4; ++mi)
                #pragma unroll
                for (int ni = 0; ni < 4; ++ni) {
                    acc[mi][ni] = __builtin_amdgcn_mfma_f32_16x16x32_bf16(ah[mi], eh[ni], acc[mi][ni], 0, 0, 0);
                    acc[mi][ni] = __builtin_amdgcn_mfma_f32_16x16x32_bf16(al[mi], eh[ni], acc[mi][ni], 0, 0, 0);
                    acc[mi][ni] = __builtin_amdgcn_mfma_f32_16x16x32_bf16(ah[mi], el[ni], acc[mi][ni], 0, 0, 0);
                }

            asm volatile("s_waitcnt vmcnt(0)" ::: "memory");
            __syncthreads();
            cur ^= 1;
        }

        // dist + per-row top-2 update (per lane: 16 rows x 4 cols)
        #pragma unroll
        for (int ni = 0; ni < 4; ++ni) {
            const int col_l = wn * 64 + ni * 16 + (lane & 15);
            const float e2 = e2s[ntl * 128 + col_l];
            const int idx = nh * 4096 + ntl * 128 + col_l;
            #pragma unroll
            for (int mi = 0; mi < 4; ++mi)
                #pragma unroll
                for (int r = 0; r < 4; ++r) {
                    const int s = mi * 4 + r;
                    float d = __builtin_fmaf(-2.f, acc[mi][ni][r], e2 + z2r[s]);
                    if (d < d1v[s] || (d == d1v[s] && idx < i1v[s])) {
                        d2v[s] = d1v[s]; i2v[s] = i1v[s]; d1v[s] = d; i1v[s] = idx;
                    } else if (d < d2v[s] || (d == d2v[s] && idx < i2v[s])) {
                        d2v[s] = d; i2v[s] = idx;
                    }
                }
        }
    }

    // cross-lane top-2 merge over the 16 col-lanes (xor bits 0..3)
    #pragma unroll
    for (int s = 0; s < 16; ++s) {
        float d1 = d1v[s], d2 = d2v[s]; int i1 = i1v[s], i2 = i2v[s];
        #pragma unroll
        for (int m = 1; m < 16; m <<= 1) {
            float od1 = __shfl_xor(d1, m, 64), od2 = __shfl_xor(d2, m, 64);
            int   oi1 = __shfl_xor(i1, m, 64), oi2 = __shfl_xor(i2, m, 64);
            bool owins = (od1 < d1) || (od1 == d1 && oi1 < i1);
            float a1 = owins ? od1 : d1;  int a1i = owins ? oi1 : i1;
            float r1 = owins ? d1  : od1; int r1i = owins ? i1  : oi1;
            float r2 = owins ? od2 : d2;  int r2i = owins ? oi2 : i2;
            bool rwins = (r2 < r1) || (r2 == r1 && r2i < r1i);
            d1 = a1; i1 = a1i;
            d2 = rwins ? r2 : r1; i2 = rwins ? r2i : r1i;
        }
        d1v[s] = d1; d2v[s] = d2; i1v[s] = i1; i2v[s] = i2;
    }
    // per-wave slot: lists from (nh, wn) cover disjoint column sets
    if ((lane & 15) == 0) {
        const int slot = nh * 2 + wn;
        #pragma unroll
        for (int mi = 0; mi < 4; ++mi)
            #pragma unroll
            for (int r = 0; r < 4; ++r) {
                const int s = mi * 4 + r;
                int grow = rowbase + mi * 16 + r;
                float4 v; v.x = d1v[s]; v.y = d2v[s];
                v.z = __int_as_float(i1v[s]); v.w = __int_as_float(i2v[s]);
                res[slot * N_ROWS + grow] = v;
            }
    }
}

// merge 4 lists (8 candidates) + exact fp32 recheck of near-ties
__global__ void merge_kernel(const float* __restrict__ x, const float* __restrict__ embed,
                             const float* __restrict__ e_norm, const float* __restrict__ z2,
                             const float4* __restrict__ res, int* __restrict__ ids_final) {
    int row = blockIdx.x * 256 + threadIdx.x;
    float d[8]; int ci[8];
    #pragma unroll
    for (int q = 0; q < 4; ++q) {
        float4 v = res[q * N_ROWS + row];
        d[2 * q] = v.x;     ci[2 * q] = __float_as_int(v.z);
        d[2 * q + 1] = v.y; ci[2 * q + 1] = __float_as_int(v.w);
    }
    float w1 = INFINITY; int wi = 0x7fffffff;
    #pragma unroll
    for (int q = 0; q < 8; ++q)
        if (d[q] < w1 || (d[q] == w1 && ci[q] < wi)) { w1 = d[q]; wi = ci[q]; }
    float w2 = INFINITY;
    #pragma unroll
    for (int q = 0; q < 8; ++q)
        if (ci[q] != wi && d[q] < w2) w2 = d[q];

    int id = wi;
    if (w2 - w1 <= TAU) {
        int b = row >> 10, t = row & 1023;
        const float* xb = x + b * (C_DIM * HW) + t;
        float dot[8] = {0.f,0.f,0.f,0.f,0.f,0.f,0.f,0.f};
        for (int c = 0; c < C_DIM; ++c) {
            float xv = xb[c << 10];
            #pragma unroll
            for (int q = 0; q < 8; ++q)
                dot[q] = __builtin_fmaf(xv, embed[(c << 13) + ci[q]], dot[q]);
        }
        float zz = z2[row];
        float bd = INFINITY; int bi = 0x7fffffff;
        #pragma unroll
        for (int q = 0; q < 8; ++q) {
            float dd = __fadd_rn(__fadd_rn(e_norm[ci[q]], zz), -__fmul_rn(2.0f, dot[q]));
            if (dd < bd || (dd == bd && ci[q] < bi)) { bd = dd; bi = ci[q]; }
        }
        id = bi;
    }
    ids_final[row] = id;
}

__global__ void out_kernel(const float* __restrict__ embed, const int* __restrict__ ids_final,
                           float* __restrict__ out, float* __restrict__ ids_out) {
    const int blk = blockIdx.x;        // 512 = b(32) x tchunk(16)
    const int b = blk >> 4, t0 = (blk & 15) << 6;
    const int tid = threadIdx.x;
    const int t_off = tid & 63, w4 = tid >> 6;

    if (tid < 64) {
        int t = t0 + tid;
        int id = ids_final[(b << 10) + t];
        int n = (b << 10) + ((t & 31) << 5) + (t >> 5);   // x-order (h,w) -> flatten order (w,h)
        ids_out[n] = (float)id;
    }
    const int myid = ids_final[(b << 10) + t0 + t_off];
    const float* ecol = embed + myid;
    float* ob = out + b * (C_DIM * HW) + t0 + t_off;
    #pragma unroll 4
    for (int c = w4; c < C_DIM; c += 4)
        ob[c * HW] = ecol[c * K_DIM];
}

extern "C" void kernel_launch(void* const* d_in, const int* in_sizes, int n_in,
                              void* d_out, int out_size, void* d_ws, size_t ws_size,
                              hipStream_t stream) {
    const float* x     = (const float*)d_in[0];
    const float* embed = (const float*)d_in[1];
    float* out = (float*)d_out;
    float* ids_out = out + N_OUT;

    // ws: ebuf(8MB) | e_norm(32KB) | z2(128KB) | res(2MB) | ids_final(128KB)
    unsigned short* ebuf = (unsigned short*)d_ws;
    float* e_norm = (float*)((char*)d_ws + 8u * 1024u * 1024u);
    float* z2     = e_norm + K_DIM;
    float4* res   = (float4*)(z2 + N_ROWS);
    int* ids_final = (int*)(res + 4 * N_ROWS);

    // Abuf (32MB) lives in d_out as scratch; fully rewritten by out_kernel at the end.
    unsigned short* abuf = (unsigned short*)d_out;

    enorm_kernel<<<K_DIM / 256, 256, 0, stream>>>(embed, e_norm);
    z2_kernel<<<N_ROWS / 256, 256, 0, stream>>>(x, z2);
    prepA_kernel<<<2048, 256, 0, stream>>>(x, abuf);
    prepE_kernel<<<512, 256, 0, stream>>>(embed, ebuf);
    vq_main<<<512, 256, 0, stream>>>(abuf, ebuf, e_norm, z2, res);
    merge_kernel<<<N_ROWS / 256, 256, 0, stream>>>(x, embed, e_norm, z2, res, ids_final);
    out_kernel<<<512, 256, 0, stream>>>(embed, ids_final, out, ids_out);
}

// Round 5
// 560.357 us; speedup vs baseline: 3.8424x; 2.1078x over previous
//
#include <hip/hip_runtime.h>
#include <math.h>

typedef float f32x4 __attribute__((ext_vector_type(4)));
typedef __attribute__((ext_vector_type(8))) short short8;

#define C_DIM  256
#define K_DIM  8192
#define HW     1024
#define N_ROWS 32768
#define N_OUT  8388608
#define TAU    0.75f

// ---------------- bf16 split helpers (RN-even) ----------------
__device__ __forceinline__ unsigned short f2bf(float v) {
    union { float f; unsigned u; } a; a.f = v;
    unsigned r = a.u + 0x7fffu + ((a.u >> 16) & 1u);
    return (unsigned short)(r >> 16);
}
__device__ __forceinline__ float bf2f(unsigned short b) {
    union { float f; unsigned u; } a; a.u = ((unsigned)b) << 16; return a.f;
}

__global__ void enorm_kernel(const float* __restrict__ embed, float* __restrict__ e_norm) {
    int k = blockIdx.x * 256 + threadIdx.x;
    float s = 0.f;
    #pragma unroll 8
    for (int c = 0; c < C_DIM; ++c) { float v = embed[c * K_DIM + k]; s = __builtin_fmaf(v, v, s); }
    e_norm[k] = s;
}

__global__ void z2_kernel(const float* __restrict__ x, float* __restrict__ z2) {
    int r = blockIdx.x * 256 + threadIdx.x;
    int b = r >> 10, t = r & 1023;
    const float* xb = x + b * (C_DIM * HW) + t;
    float s = 0.f;
    #pragma unroll 8
    for (int c = 0; c < C_DIM; ++c) { float v = xb[c << 10]; s = __builtin_fmaf(v, v, s); }
    z2[r] = s;
}

// abuf (A_hi only): [blk 128][ck 8][frag 16][lane 64][e 8] ushort = 16 MB
// row = blk*256 + frag*16 + (lane&15); ch = ck*32 + (lane>>4)*8 + e
__global__ void prepA_kernel(const float* __restrict__ x, unsigned short* __restrict__ abuf) {
    int u = blockIdx.x * 256 + threadIdx.x;       // 1,048,576 units
    int l = u & 63;
    int f = (u >> 6) & 15;
    int ck = (u >> 10) & 7;
    int blk = u >> 13;
    int row = (blk << 8) + (f << 4) + (l & 15);
    int ch0 = (ck << 5) + ((l >> 4) << 3);
    int b = row >> 10, t = row & 1023;
    const float* xp = x + ((size_t)((b << 8) + ch0) << 10) + t;
    short8 hi;
    #pragma unroll
    for (int j = 0; j < 8; ++j) hi[j] = (short)f2bf(xp[(size_t)j << 10]);
    *(short8*)(abuf + (size_t)u * 8) = hi;
}

// ebuf (E hi+lo): [nt 128][ck 8][s 2][frag 4][lane 64][e 8] ushort = 8 MB
// col = nt*64 + frag*16 + (lane&15); ch = ck*32 + (lane>>4)*8 + e
__global__ void prepE_kernel(const float* __restrict__ embed, unsigned short* __restrict__ ebuf) {
    int u = blockIdx.x * 256 + threadIdx.x;       // 524,288 units
    int l = u & 63;
    int f = (u >> 6) & 3;
    int s = (u >> 8) & 1;
    int ck = (u >> 9) & 7;
    int nt = u >> 12;
    int col = (nt << 6) + (f << 4) + (l & 15);
    int ch0 = (ck << 5) + ((l >> 4) << 3);
    short8 w;
    #pragma unroll
    for (int j = 0; j < 8; ++j) {
        float v = embed[(size_t)(ch0 + j) * K_DIM + col];
        unsigned short h = f2bf(v);
        w[j] = (short)(s ? f2bf(v - bf2f(h)) : h);
    }
    *(short8*)(ebuf + (size_t)u * 8) = w;
}

#define GLDS(S, D) __builtin_amdgcn_global_load_lds(                              \
        (const __attribute__((address_space(1))) void*)(S),                       \
        (__attribute__((address_space(3))) void*)(D), 16, 0, 0)

// main: 256 blocks x 512 thr (8 waves = 4 wm x 2 wn). Block = 256 rows x 4096 cols.
// A_hi resident in LDS (ck0..6) + regs (ck7). E (hi+lo) double-buffered 64-col chunks.
// P=2 split GEMM: a.e ~= ah*eh + ah*el. Fused per-lane top-2, 8 col-disjoint lists/row.
__launch_bounds__(512, 2)
__global__ void vq_main(const unsigned short* __restrict__ abuf,
                        const unsigned short* __restrict__ ebuf,
                        const float* __restrict__ e_norm,
                        float4* __restrict__ res) {
    __shared__ unsigned short ldsA[57344];        // 112 KB: ck0..6
    __shared__ unsigned short ldsE[2][8192];      // 2 x 16 KB
    const int tid  = threadIdx.x;
    const int lane = tid & 63;
    const int wid  = tid >> 6;
    const int wm   = wid >> 1, wn = wid & 1;
    const int mtB  = blockIdx.x >> 1, nh = blockIdx.x & 1;
    const unsigned short* aSlab = abuf + (size_t)mtB * 65536u;

    // one-time A stage (ck0..6, contiguous 112 KB)
    #pragma unroll
    for (int i = 0; i < 14; ++i)
        GLDS(aSlab + i * 4096 + tid * 8, ldsA + i * 4096 + tid * 8);

    #define STAGE_E(NTL, KK, BUF) do {                                                        \
        GLDS(ebuf + ((size_t)(nh * 64 + (NTL)) * 32768u) + (KK) * 4096 + tid * 8,             \
             &ldsE[BUF][tid * 8]);                                                            \
        GLDS(ebuf + ((size_t)(nh * 64 + 32 + (NTL)) * 32768u) + (KK) * 4096 + tid * 8,        \
             &ldsE[BUF][4096 + tid * 8]);                                                     \
    } while (0)

    STAGE_E(0, 0, 0);   // phase-0 prologue

    // A ck7 in regs
    short8 a7[4];
    #pragma unroll
    for (int mi = 0; mi < 4; ++mi)
        a7[mi] = *(const short8*)(aSlab + 57344 + (wm * 4 + mi) * 512 + lane * 8);

    float d1[16], d2[16]; int i1[16], i2[16];
    #pragma unroll
    for (int s = 0; s < 16; ++s) { d1[s] = INFINITY; d2[s] = INFINITY; i1[s] = 0; i2[s] = 0; }

    asm volatile("s_waitcnt vmcnt(0)" ::: "memory");
    __syncthreads();

    int cur = 0;
    #pragma unroll 1
    for (int ntl = 0; ntl < 32; ++ntl) {
        const int colb = nh * 4096 + wn * 2048 + ntl * 64 + (lane & 15);
        float e2v[4];
        #pragma unroll
        for (int cf = 0; cf < 4; ++cf) e2v[cf] = e_norm[colb + cf * 16];

        f32x4 acc[4][4];
        #pragma unroll
        for (int mi = 0; mi < 4; ++mi)
            #pragma unroll
            for (int cf = 0; cf < 4; ++cf) acc[mi][cf] = (f32x4){0.f, 0.f, 0.f, 0.f};

        #pragma unroll
        for (int kk = 0; kk < 8; ++kk) {
            const int np = ntl * 8 + kk + 1;
            if (np < 256) STAGE_E(np >> 3, np & 7, cur ^ 1);

            short8 ah[4];
            if (kk < 7) {
                #pragma unroll
                for (int mi = 0; mi < 4; ++mi)
                    ah[mi] = *(const short8*)(ldsA + kk * 8192 + (wm * 4 + mi) * 512 + lane * 8);
            } else {
                #pragma unroll
                for (int mi = 0; mi < 4; ++mi) ah[mi] = a7[mi];
            }
            short8 eh[4], el[4];
            #pragma unroll
            for (int cf = 0; cf < 4; ++cf) {
                eh[cf] = *(const short8*)(&ldsE[cur][wn * 4096 + cf * 512 + lane * 8]);
                el[cf] = *(const short8*)(&ldsE[cur][wn * 4096 + 2048 + cf * 512 + lane * 8]);
            }
            #pragma unroll
            for (int cf = 0; cf < 4; ++cf)
                #pragma unroll
                for (int mi = 0; mi < 4; ++mi) {
                    acc[mi][cf] = __builtin_amdgcn_mfma_f32_16x16x32_bf16(ah[mi], eh[cf], acc[mi][cf], 0, 0, 0);
                    acc[mi][cf] = __builtin_amdgcn_mfma_f32_16x16x32_bf16(ah[mi], el[cf], acc[mi][cf], 0, 0, 0);
                }
            asm volatile("s_waitcnt vmcnt(0)" ::: "memory");
            __syncthreads();
            cur ^= 1;
        }

        // top-2 update (cmp scale: e2 - 2*dot; z2 row-constant cancels)
        #pragma unroll
        for (int cf = 0; cf < 4; ++cf) {
            const int idx = colb + cf * 16;
            #pragma unroll
            for (int mi = 0; mi < 4; ++mi)
                #pragma unroll
                for (int r = 0; r < 4; ++r) {
                    const int s = mi * 4 + r;
                    float d = __builtin_fmaf(-2.f, acc[mi][cf][r], e2v[cf]);
                    bool b1 = d < d1[s];
                    bool b2 = d < d2[s];
                    d2[s] = b1 ? d1[s] : (b2 ? d : d2[s]);
                    i2[s] = b1 ? i1[s] : (b2 ? idx : i2[s]);
                    d1[s] = b1 ? d : d1[s];
                    i1[s] = b1 ? idx : i1[s];
                }
        }
    }

    // reduce top-2 across lane bits 0..2 -> 2 lists per (row, wave), lst = lane bit 3
    #pragma unroll
    for (int s = 0; s < 16; ++s) {
        float a1 = d1[s], a2 = d2[s]; int x1 = i1[s], x2 = i2[s];
        #pragma unroll
        for (int m = 1; m < 8; m <<= 1) {
            float o1 = __shfl_xor(a1, m, 64), o2 = __shfl_xor(a2, m, 64);
            int  oi1 = __shfl_xor(x1, m, 64), oi2 = __shfl_xor(x2, m, 64);
            bool ow = (o1 < a1) || (o1 == a1 && oi1 < x1);
            float w1v = ow ? o1 : a1; int w1i = ow ? oi1 : x1;
            float l1  = ow ? a1 : o1; int l1i = ow ? x1 : oi1;
            float c2  = ow ? o2 : a2; int c2i = ow ? oi2 : x2;
            bool sw = (c2 < l1) || (c2 == l1 && c2i < l1i);
            a1 = w1v; x1 = w1i;
            a2 = sw ? c2 : l1; x2 = sw ? c2i : l1i;
        }
        d1[s] = a1; d2[s] = a2; i1[s] = x1; i2[s] = x2;
    }
    // 8 col-disjoint lists per row: slot = nh*4 + wn*2 + lst  (race-free: unique writer)
    if ((lane & 7) == 0) {
        const int lst = (lane >> 3) & 1;
        const int h = lane >> 4;
        const int slot = nh * 4 + wn * 2 + lst;
        #pragma unroll
        for (int mi = 0; mi < 4; ++mi)
            #pragma unroll
            for (int r = 0; r < 4; ++r) {
                const int s = mi * 4 + r;
                int row = mtB * 256 + wm * 64 + mi * 16 + h * 4 + r;
                float4 v; v.x = d1[s]; v.y = d2[s];
                v.z = __int_as_float(i1[s]); v.w = __int_as_float(i2[s]);
                res[row * 8 + slot] = v;
            }
    }
    #undef STAGE_E
}

// merge 8 lists (16 cands, col-disjoint) + exact fp32 recheck of near-ties
__global__ void merge_kernel(const float* __restrict__ x, const float* __restrict__ embed,
                             const float* __restrict__ e_norm, const float* __restrict__ z2,
                             const float4* __restrict__ res, int* __restrict__ ids_final) {
    int row = blockIdx.x * 256 + threadIdx.x;
    float4 v[8];
    #pragma unroll
    for (int j = 0; j < 8; ++j) v[j] = res[row * 8 + j];
    float w1 = INFINITY; int wi = 0x7fffffff;
    #pragma unroll
    for (int j = 0; j < 8; ++j) {
        float d = v[j].x; int i = __float_as_int(v[j].z);
        if (d < w1 || (d == w1 && i < wi)) { w1 = d; wi = i; }
    }
    float w2 = INFINITY;
    #pragma unroll
    for (int j = 0; j < 8; ++j) {
        if (__float_as_int(v[j].z) != wi && v[j].x < w2) w2 = v[j].x;
        if (__float_as_int(v[j].w) != wi && v[j].y < w2) w2 = v[j].y;
    }
    int id = wi;
    if (w2 - w1 <= TAU) {
        float zz = z2[row];
        int b = row >> 10, t = row & 1023;
        const float* xb = x + ((size_t)b << 18) + t;
        float bd = INFINITY; int bi = 0x7fffffff;
        float thr = w1 + TAU;
        #pragma unroll
        for (int j = 0; j < 8; ++j)
            #pragma unroll
            for (int sl = 0; sl < 2; ++sl) {
                float dap = sl ? v[j].y : v[j].x;
                int k = __float_as_int(sl ? v[j].w : v[j].z);
                if (dap <= thr) {
                    float dot = 0.f;
                    for (int c = 0; c < C_DIM; ++c)
                        dot = __builtin_fmaf(xb[(size_t)c << 10], embed[((size_t)c << 13) + k], dot);
                    float dd = __fadd_rn(__fadd_rn(e_norm[k], zz), -__fmul_rn(2.0f, dot));
                    if (dd < bd || (dd == bd && k < bi)) { bd = dd; bi = k; }
                }
            }
        id = bi;
    }
    ids_final[row] = id;
}

__global__ void out_kernel(const float* __restrict__ embed, const int* __restrict__ ids_final,
                           float* __restrict__ out, float* __restrict__ ids_out) {
    const int blk = blockIdx.x;        // 512 = b(32) x tchunk(16)
    const int b = blk >> 4, t0 = (blk & 15) << 6;
    const int tid = threadIdx.x;
    const int t_off = tid & 63, w4 = tid >> 6;

    if (tid < 64) {
        int t = t0 + tid;
        int id = ids_final[(b << 10) + t];
        int n = (b << 10) + ((t & 31) << 5) + (t >> 5);   // x-order (h,w) -> flatten (w,h)
        ids_out[n] = (float)id;
    }
    const int myid = ids_final[(b << 10) + t0 + t_off];
    const float* ecol = embed + myid;
    float* ob = out + b * (C_DIM * HW) + t0 + t_off;
    #pragma unroll 4
    for (int c = w4; c < C_DIM; c += 4)
        ob[c * HW] = ecol[c * K_DIM];
}

extern "C" void kernel_launch(void* const* d_in, const int* in_sizes, int n_in,
                              void* d_out, int out_size, void* d_ws, size_t ws_size,
                              hipStream_t stream) {
    const float* x     = (const float*)d_in[0];
    const float* embed = (const float*)d_in[1];
    float* out = (float*)d_out;
    float* ids_out = out + N_OUT;

    // d_out scratch (sequential lifetimes, disjoint regions):
    //   abuf 16 MB @ [0,16M)   — consumed by vq_main A-staging
    //   res   4 MB @ [16M,20M) — written end of vq_main, read by merge
    // out_kernel overwrites everything afterward.
    unsigned short* abuf = (unsigned short*)d_out;
    float4* res = (float4*)((char*)d_out + (16u << 20));

    // ws: ebuf 8 MB | e_norm 32 KB | z2 128 KB | ids_final 128 KB  (~8.3 MB)
    unsigned short* ebuf = (unsigned short*)d_ws;
    float* e_norm   = (float*)((char*)d_ws + (8u << 20));
    float* z2       = e_norm + K_DIM;
    int*   ids_final = (int*)(z2 + N_ROWS);

    enorm_kernel<<<K_DIM / 256, 256, 0, stream>>>(embed, e_norm);
    z2_kernel<<<N_ROWS / 256, 256, 0, stream>>>(x, z2);
    prepA_kernel<<<4096, 256, 0, stream>>>(x, abuf);
    prepE_kernel<<<2048, 256, 0, stream>>>(embed, ebuf);
    vq_main<<<256, 512, 0, stream>>>(abuf, ebuf, e_norm, res);
    merge_kernel<<<N_ROWS / 256, 256, 0, stream>>>(x, embed, e_norm, z2, res, ids_final);
    out_kernel<<<512, 256, 0, stream>>>(embed, ids_final, out, ids_out);
}

// Round 6
// 533.123 us; speedup vs baseline: 4.0387x; 1.0511x over previous
//
#include <hip/hip_runtime.h>
#include <math.h>

typedef float f32x4 __attribute__((ext_vector_type(4)));
typedef __attribute__((ext_vector_type(8))) short short8;

#define C_DIM  256
#define K_DIM  8192
#define HW     1024
#define N_ROWS 32768
#define N_OUT  8388608
#define TAU    0.75f

// ---------------- bf16 split helpers (RN-even) ----------------
__device__ __forceinline__ unsigned short f2bf(float v) {
    union { float f; unsigned u; } a; a.f = v;
    unsigned r = a.u + 0x7fffu + ((a.u >> 16) & 1u);
    return (unsigned short)(r >> 16);
}
__device__ __forceinline__ float bf2f(unsigned short b) {
    union { float f; unsigned u; } a; a.u = ((unsigned)b) << 16; return a.f;
}

// abuf (A_hi): [blk 128][ck 8][frag 16][lane 64][e 8] ushort = 16 MB
//   row = blk*256 + frag*16 + (lane&15); ch = ck*32 + (lane>>4)*8 + e
// ebuf (E hi+lo): [nt 128][ck 8][s 2][frag 4][lane 64][e 8] ushort = 8 MB
//   col = nt*64 + frag*16 + (lane&15); ch = ck*32 + (lane>>4)*8 + e

// ---------------- prepA: LDS-transposed, fully coalesced ----------------
__global__ void prepA_kernel(const float* __restrict__ x, unsigned short* __restrict__ abuf) {
    __shared__ float ldsT[256 * 65];
    const int tid = threadIdx.x;
    const int b = blockIdx.x >> 4, tq = blockIdx.x & 15;
    const int t0 = tq << 6;
    const int l = tid & 63, q = tid >> 6;
    const float* xb = x + ((size_t)b << 18) + t0;
    #pragma unroll 8
    for (int cg = 0; cg < 64; ++cg) {
        int c = (cg << 2) + q;
        ldsT[c * 65 + l] = xb[((size_t)c << 10) + l];     // 256B contiguous / wave
    }
    __syncthreads();
    const int slabblk = (b << 2) + (tq >> 2);
    const int fbase = (tq & 3) << 2;
    #pragma unroll
    for (int i = 0; i < 8; ++i) {
        int unit = (i << 2) + q;            // 0..31 = ck(8) x fsub(4)
        int ck = unit >> 2, fsub = unit & 3;
        int toff = (fsub << 4) + (l & 15);
        int ch0 = (ck << 5) + ((l >> 4) << 3);
        short8 hi;
        #pragma unroll
        for (int j = 0; j < 8; ++j) hi[j] = (short)f2bf(ldsT[(ch0 + j) * 65 + toff]);
        size_t base = (((size_t)slabblk * 8 + ck) * 16 + fbase + fsub) * 512 + l * 8;
        *(short8*)(abuf + base) = hi;       // 1KB contiguous / wave
    }
}

// ---------------- prepE: LDS-transposed; also e_norm and (optional) embedT ----------------
__global__ void prepE_kernel(const float* __restrict__ embed, unsigned short* __restrict__ ebuf,
                             float* __restrict__ e_norm, float* __restrict__ embedT) {
    __shared__ float ldsT[256 * 65];
    __shared__ float pnorm[256];
    const int tid = threadIdx.x;
    const int kq = blockIdx.x;              // 0..127
    const int col0 = kq << 6;
    const int l = tid & 63, q = tid >> 6;
    #pragma unroll 8
    for (int cg = 0; cg < 64; ++cg) {
        int c = (cg << 2) + q;
        ldsT[c * 65 + l] = embed[((size_t)c << 13) + col0 + l];
    }
    __syncthreads();
    {
        float s = 0.f;
        #pragma unroll 8
        for (int cc = 0; cc < 64; ++cc) {
            float v = ldsT[(q * 64 + cc) * 65 + l];
            s = __builtin_fmaf(v, v, s);
        }
        pnorm[q * 64 + l] = s;
    }
    __syncthreads();
    if (tid < 64)
        e_norm[col0 + tid] = (pnorm[tid] + pnorm[64 + tid]) + (pnorm[128 + tid] + pnorm[192 + tid]);
    #pragma unroll
    for (int i = 0; i < 16; ++i) {
        int unit = (i << 2) + q;            // 0..63 = ck(8) x s(2) x f(4)
        int f = unit & 3, s = (unit >> 2) & 1, ck = unit >> 3;
        int coff = (f << 4) + (l & 15);
        int ch0 = (ck << 5) + ((l >> 4) << 3);
        short8 w;
        #pragma unroll
        for (int j = 0; j < 8; ++j) {
            float v = ldsT[(ch0 + j) * 65 + coff];
            unsigned short h = f2bf(v);
            w[j] = (short)(s ? f2bf(v - bf2f(h)) : h);
        }
        size_t base = ((((size_t)kq * 8 + ck) * 2 + s) * 4 + f) * 512 + l * 8;
        *(short8*)(ebuf + base) = w;
    }
    if (embedT) {
        #pragma unroll 8
        for (int i = 0; i < 64; ++i)
            embedT[(size_t)(col0 + i) * 256 + tid] = ldsT[tid * 65 + i];
    }
}

#define GLDS(S, D) __builtin_amdgcn_global_load_lds(                              \
        (const __attribute__((address_space(1))) void*)(S),                       \
        (__attribute__((address_space(3))) void*)(D), 16, 0, 0)

// main: 256 blocks x 512 thr (8 waves = 4 wm x 2 wn). Block = 256 rows x 4096 cols.
// A_hi: ck0..5 in LDS, a6/a7 in regs. E: 3-buffer pipeline, counted vmcnt(2),
// raw barriers (no per-phase full drain). P=2 split: a.e ~= ah*eh + ah*el.
__launch_bounds__(512, 2)
__global__ void vq_main(const unsigned short* __restrict__ abuf,
                        const unsigned short* __restrict__ ebuf,
                        const float* __restrict__ e_norm,
                        float4* __restrict__ res) {
    __shared__ unsigned short ldsA[49152];      // 96 KB: ck0..5
    __shared__ unsigned short ldsE[3][8192];    // 3 x 16 KB
    const int tid  = threadIdx.x;
    const int lane = tid & 63;
    const int wid  = tid >> 6;
    const int wm   = wid >> 1, wn = wid & 1;
    const int mtB  = blockIdx.x >> 1, nh = blockIdx.x & 1;
    const unsigned short* aSlab = abuf + (size_t)mtB * 65536u;

    #define STAGE_E(NTL, KK, BUF) do {                                                        \
        GLDS(ebuf + ((size_t)(nh * 64 + (NTL)) * 32768u) + (KK) * 4096 + tid * 8,             \
             &ldsE[BUF][tid * 8]);                                                            \
        GLDS(ebuf + ((size_t)(nh * 64 + 32 + (NTL)) * 32768u) + (KK) * 4096 + tid * 8,        \
             &ldsE[BUF][4096 + tid * 8]);                                                     \
    } while (0)

    // prologue: A ck0..5 (12 x 8KB), E phase 0; a6/a7 reg loads; full drain once
    #pragma unroll
    for (int i = 0; i < 12; ++i)
        GLDS(aSlab + i * 4096 + tid * 8, ldsA + i * 4096 + tid * 8);
    STAGE_E(0, 0, 0);

    short8 a6[4], a7[4];
    #pragma unroll
    for (int mi = 0; mi < 4; ++mi) {
        a6[mi] = *(const short8*)(aSlab + 6 * 8192 + (wm * 4 + mi) * 512 + lane * 8);
        a7[mi] = *(const short8*)(aSlab + 7 * 8192 + (wm * 4 + mi) * 512 + lane * 8);
    }

    float d1[16], d2[16]; int i1[16], i2[16];
    #pragma unroll
    for (int s = 0; s < 16; ++s) { d1[s] = INFINITY; d2[s] = INFINITY; i1[s] = 0; i2[s] = 0; }

    asm volatile("s_waitcnt vmcnt(0)" ::: "memory");
    __syncthreads();
    STAGE_E(0, 1, 1);               // phase-1 stage (in flight across phase 0)

    int cur = 0;
    #pragma unroll 1
    for (int ntl = 0; ntl < 32; ++ntl) {
        const int colb = nh * 4096 + wn * 2048 + ntl * 64 + (lane & 15);
        float e2v[4];
        f32x4 acc[4][4];
        #pragma unroll
        for (int mi = 0; mi < 4; ++mi)
            #pragma unroll
            for (int cf = 0; cf < 4; ++cf) acc[mi][cf] = (f32x4){0.f, 0.f, 0.f, 0.f};

        #pragma unroll
        for (int kk = 0; kk < 8; ++kk) {
            // own slices of stage(p) retired (stage(p+1) may stay in flight)
            if (kk == 7 && ntl == 31) { asm volatile("s_waitcnt vmcnt(0)" ::: "memory"); }
            else                      { asm volatile("s_waitcnt vmcnt(2)" ::: "memory"); }
            __builtin_amdgcn_s_barrier();
            asm volatile("" ::: "memory");

            if (kk == 0) {          // issued BEFORE this phase's stage -> keeps vmcnt count safe
                #pragma unroll
                for (int cf = 0; cf < 4; ++cf) e2v[cf] = e_norm[colb + cf * 16];
            }
            const int np = ntl * 8 + kk + 2;
            if (np < 256) {
                int nb = cur + 2; if (nb >= 3) nb -= 3;
                STAGE_E(np >> 3, np & 7, nb);
            }

            short8 ah[4];
            if (kk < 6) {
                #pragma unroll
                for (int mi = 0; mi < 4; ++mi)
                    ah[mi] = *(const short8*)(ldsA + kk * 8192 + (wm * 4 + mi) * 512 + lane * 8);
            } else if (kk == 6) {
                #pragma unroll
                for (int mi = 0; mi < 4; ++mi) ah[mi] = a6[mi];
            } else {
                #pragma unroll
                for (int mi = 0; mi < 4; ++mi) ah[mi] = a7[mi];
            }
            const unsigned short* le = ldsE[cur];
            short8 eh[4], el[4];
            #pragma unroll
            for (int cf = 0; cf < 4; ++cf) {
                eh[cf] = *(const short8*)(le + wn * 4096 + cf * 512 + lane * 8);
                el[cf] = *(const short8*)(le + wn * 4096 + 2048 + cf * 512 + lane * 8);
            }
            __builtin_amdgcn_s_setprio(1);
            #pragma unroll
            for (int cf = 0; cf < 4; ++cf)
                #pragma unroll
                for (int mi = 0; mi < 4; ++mi) {
                    acc[mi][cf] = __builtin_amdgcn_mfma_f32_16x16x32_bf16(ah[mi], eh[cf], acc[mi][cf], 0, 0, 0);
                    acc[mi][cf] = __builtin_amdgcn_mfma_f32_16x16x32_bf16(ah[mi], el[cf], acc[mi][cf], 0, 0, 0);
                }
            __builtin_amdgcn_s_setprio(0);
            cur = (cur == 2) ? 0 : cur + 1;
        }

        // top-2 update (cmp scale: e2 - 2*dot; z2 row-constant cancels)
        #pragma unroll
        for (int cf = 0; cf < 4; ++cf) {
            const int idx = colb + cf * 16;
            #pragma unroll
            for (int mi = 0; mi < 4; ++mi)
                #pragma unroll
                for (int r = 0; r < 4; ++r) {
                    const int s = mi * 4 + r;
                    float d = __builtin_fmaf(-2.f, acc[mi][cf][r], e2v[cf]);
                    bool b1 = d < d1[s];
                    bool b2 = d < d2[s];
                    d2[s] = b1 ? d1[s] : (b2 ? d : d2[s]);
                    i2[s] = b1 ? i1[s] : (b2 ? idx : i2[s]);
                    d1[s] = b1 ? d : d1[s];
                    i1[s] = b1 ? idx : i1[s];
                }
        }
    }

    // reduce top-2 across lane bits 0..2 -> 2 lists per (row, wave), lst = lane bit 3
    #pragma unroll
    for (int s = 0; s < 16; ++s) {
        float a1 = d1[s], a2 = d2[s]; int x1 = i1[s], x2 = i2[s];
        #pragma unroll
        for (int m = 1; m < 8; m <<= 1) {
            float o1 = __shfl_xor(a1, m, 64), o2 = __shfl_xor(a2, m, 64);
            int  oi1 = __shfl_xor(x1, m, 64), oi2 = __shfl_xor(x2, m, 64);
            bool ow = (o1 < a1) || (o1 == a1 && oi1 < x1);
            float w1v = ow ? o1 : a1; int w1i = ow ? oi1 : x1;
            float l1  = ow ? a1 : o1; int l1i = ow ? x1 : oi1;
            float c2  = ow ? o2 : a2; int c2i = ow ? oi2 : x2;
            bool sw = (c2 < l1) || (c2 == l1 && c2i < l1i);
            a1 = w1v; x1 = w1i;
            a2 = sw ? c2 : l1; x2 = sw ? c2i : l1i;
        }
        d1[s] = a1; d2[s] = a2; i1[s] = x1; i2[s] = x2;
    }
    // 8 col-disjoint lists per row: slot = nh*4 + wn*2 + lst  (unique writer)
    if ((lane & 7) == 0) {
        const int lst = (lane >> 3) & 1;
        const int h = lane >> 4;
        const int slot = nh * 4 + wn * 2 + lst;
        const int rowbase = (mtB << 8) + wm * 64 + (h << 2);
        #pragma unroll
        for (int mi = 0; mi < 4; ++mi)
            #pragma unroll
            for (int r = 0; r < 4; ++r) {
                const int s = mi * 4 + r;
                int row = rowbase + mi * 16 + r;
                float4 v; v.x = d1[s]; v.y = d2[s];
                v.z = __int_as_float(i1[s]); v.w = __int_as_float(i2[s]);
                res[row * 8 + slot] = v;
            }
    }
    #undef STAGE_E
}

// merge 8 lists (16 cands, col-disjoint) + exact fp32 recheck of near-ties
__global__ void merge_kernel(const float* __restrict__ x, const float* __restrict__ embed,
                             const float* __restrict__ e_norm,
                             const float4* __restrict__ res, int* __restrict__ ids_final) {
    int row = blockIdx.x * 256 + threadIdx.x;
    float4 v[8];
    #pragma unroll
    for (int j = 0; j < 8; ++j) v[j] = res[row * 8 + j];
    float w1 = INFINITY; int wi = 0x7fffffff;
    #pragma unroll
    for (int j = 0; j < 8; ++j) {
        float d = v[j].x; int i = __float_as_int(v[j].z);
        if (d < w1 || (d == w1 && i < wi)) { w1 = d; wi = i; }
    }
    float w2 = INFINITY;
    #pragma unroll
    for (int j = 0; j < 8; ++j) {
        if (__float_as_int(v[j].z) != wi && v[j].x < w2) w2 = v[j].x;
        if (__float_as_int(v[j].w) != wi && v[j].y < w2) w2 = v[j].y;
    }
    int id = wi;
    if (w2 - w1 <= TAU) {
        int b = row >> 10, t = row & 1023;
        const float* xb = x + ((size_t)b << 18) + t;
        float bd = INFINITY; int bi = 0x7fffffff;
        float thr = w1 + TAU;
        #pragma unroll
        for (int j = 0; j < 8; ++j)
            #pragma unroll
            for (int sl = 0; sl < 2; ++sl) {
                float dap = sl ? v[j].y : v[j].x;
                int k = __float_as_int(sl ? v[j].w : v[j].z);
                if (dap <= thr) {
                    float dot = 0.f;
                    for (int c = 0; c < C_DIM; ++c)
                        dot = __builtin_fmaf(xb[(size_t)c << 10], embed[((size_t)c << 13) + k], dot);
                    float dd = __fadd_rn(e_norm[k], -__fmul_rn(2.0f, dot));
                    if (dd < bd || (dd == bd && k < bi)) { bd = dd; bi = k; }
                }
            }
        id = bi;
    }
    ids_final[row] = id;
}

// out via embedT: contiguous 1KB row gathers staged through padded LDS
__global__ void outT_kernel(const float* __restrict__ embedT, const int* __restrict__ ids_final,
                            float* __restrict__ out, float* __restrict__ ids_out) {
    __shared__ float fo[64 * 257];
    __shared__ int idsl[64];
    const int blk = blockIdx.x;         // 512 = b(32) x tchunk(16)
    const int b = blk >> 4, t0 = (blk & 15) << 6;
    const int tid = threadIdx.x;
    const int l = tid & 63, q = tid >> 6;
    if (tid < 64) {
        int t = t0 + tid;
        int id = ids_final[(b << 10) + t];
        idsl[tid] = id;
        int n = (b << 10) + ((t & 31) << 5) + (t >> 5);
        ids_out[n] = (float)id;
    }
    __syncthreads();
    #pragma unroll
    for (int i = 0; i < 16; ++i) {
        int slot = (i << 2) + q;
        const float* src = embedT + (size_t)idsl[slot] * 256;
        #pragma unroll
        for (int seg = 0; seg < 4; ++seg)
            fo[slot * 257 + (seg << 6) + l] = src[(seg << 6) + l];
    }
    __syncthreads();
    float* ob = out + ((size_t)b << 18) + t0;
    #pragma unroll 8
    for (int ci = 0; ci < 64; ++ci) {
        int c = (ci << 2) + q;
        ob[((size_t)c << 10) + l] = fo[l * 257 + c];
    }
}

// fallback out (round-5 validated): column gather from embed
__global__ void out_kernel(const float* __restrict__ embed, const int* __restrict__ ids_final,
                           float* __restrict__ out, float* __restrict__ ids_out) {
    const int blk = blockIdx.x;
    const int b = blk >> 4, t0 = (blk & 15) << 6;
    const int tid = threadIdx.x;
    const int t_off = tid & 63, w4 = tid >> 6;
    if (tid < 64) {
        int t = t0 + tid;
        int id = ids_final[(b << 10) + t];
        int n = (b << 10) + ((t & 31) << 5) + (t >> 5);
        ids_out[n] = (float)id;
    }
    const int myid = ids_final[(b << 10) + t0 + t_off];
    const float* ecol = embed + myid;
    float* ob = out + b * (C_DIM * HW) + t0 + t_off;
    #pragma unroll 4
    for (int c = w4; c < C_DIM; c += 4)
        ob[c * HW] = ecol[c * K_DIM];
}

extern "C" void kernel_launch(void* const* d_in, const int* in_sizes, int n_in,
                              void* d_out, int out_size, void* d_ws, size_t ws_size,
                              hipStream_t stream) {
    const float* x     = (const float*)d_in[0];
    const float* embed = (const float*)d_in[1];
    float* out = (float*)d_out;
    float* ids_out = out + N_OUT;

    // d_out scratch (sequential lifetimes, disjoint): abuf 16MB @0, res 4MB @16MB
    unsigned short* abuf = (unsigned short*)d_out;
    float4* res = (float4*)((char*)d_out + (16u << 20));

    // ws: ebuf 8MB | e_norm 32KB | ids_final 128KB | embedT 8MB (optional)
    unsigned short* ebuf = (unsigned short*)d_ws;
    float* e_norm    = (float*)((char*)d_ws + 8388608u);
    int*   ids_final = (int*)((char*)d_ws + 8388608u + 32768u);
    size_t embT_off  = 8388608u + 32768u + 131072u;
    bool useT = (ws_size >= embT_off + 8388608u);
    float* embedT = useT ? (float*)((char*)d_ws + embT_off) : nullptr;

    prepA_kernel<<<512, 256, 0, stream>>>(x, abuf);
    prepE_kernel<<<128, 256, 0, stream>>>(embed, ebuf, e_norm, embedT);
    vq_main<<<256, 512, 0, stream>>>(abuf, ebuf, e_norm, res);
    merge_kernel<<<N_ROWS / 256, 256, 0, stream>>>(x, embed, e_norm, res, ids_final);
    if (useT) outT_kernel<<<512, 256, 0, stream>>>(embedT, ids_final, out, ids_out);
    else      out_kernel<<<512, 256, 0, stream>>>(embed, ids_final, out, ids_out);
}